// Round 1
// baseline (616.262 us; speedup 1.0000x reference)
//
#include <hip/hip_runtime.h>
#include <math.h>

#define DD    128
#define TWOD  256
#define FOURD 512
#define NBN   30
#define BQ    4096
#define FEWN  5
#define NSYM  200000
#define KTOT  768    // 256 (query) + 256 (h) + 256 (r)
#define NGATE 1024   // 256 live units x 4 gates (units 256..511 are dead)
#define ULIVE 256
#define TOTU  (2 * BQ + 2 * FEWN)   // 8202 row-units
#define UPB   4                      // units per block (neighbor kernel)

typedef short bf16x8 __attribute__((ext_vector_type(8)));
typedef float f32x4 __attribute__((ext_vector_type(4)));

__device__ __forceinline__ float sigmoidf_(float x) { return 1.0f / (1.0f + expf(-x)); }

// fast tanh: 1 - 2/(e^{2x}+1)  (v_exp + v_rcp; |err| ~1e-6, saturates correctly)
__device__ __forceinline__ float ftanh(float x) {
    float e = __expf(2.0f * x);
    return 1.0f - 2.0f / (e + 1.0f);
}

__device__ __forceinline__ unsigned short f2bf(float f) {
    unsigned int u = __float_as_uint(f);
    unsigned int r = (u + 0x7fffu + ((u >> 16) & 1u)) >> 16;
    return (unsigned short)r;
}

// pack 8 fp32 -> bf16x8 (round-to-nearest-ish)
__device__ __forceinline__ bf16x8 pack8(float4 a, float4 b) {
    union { bf16x8 v; unsigned int u[4]; } r;
    r.u[0] = ((__float_as_uint(a.x) + 0x8000u) >> 16) | ((__float_as_uint(a.y) + 0x8000u) & 0xffff0000u);
    r.u[1] = ((__float_as_uint(a.z) + 0x8000u) >> 16) | ((__float_as_uint(a.w) + 0x8000u) & 0xffff0000u);
    r.u[2] = ((__float_as_uint(b.x) + 0x8000u) >> 16) | ((__float_as_uint(b.y) + 0x8000u) & 0xffff0000u);
    r.u[3] = ((__float_as_uint(b.z) + 0x8000u) >> 16) | ((__float_as_uint(b.w) + 0x8000u) & 0xffff0000u);
    return r.v;
}

__device__ __forceinline__ void gload_lds16(const void* g, void* l) {
    __builtin_amdgcn_global_load_lds((const __attribute__((address_space(1))) unsigned int*)g,
                                     (__attribute__((address_space(3))) unsigned int*)l,
                                     16, 0, 0);
}

// ---------------- K0: one-time weight prep -------------------------------------
__global__ __launch_bounds__(256) void k_prep(
    const float* __restrict__ Wih, const float* __restrict__ Whh,
    const float* __restrict__ bih, const float* __restrict__ bhh,
    const float* __restrict__ p1W, const float* __restrict__ p2W,
    const float* __restrict__ nW, const float* __restrict__ nvW,
    unsigned short* __restrict__ Wbf, float* __restrict__ biasR,
    float* __restrict__ p1WT, float* __restrict__ p2WT,
    unsigned short* __restrict__ Nbf)
{
    int idx = blockIdx.x * 256 + threadIdx.x;
    int stride = gridDim.x * 256;
    for (int i = idx; i < NGATE * KTOT; i += stride) {
        int n = i / KTOT, k = i - n * KTOT;
        int blk = n >> 6, rem = n & 63;
        int g = rem >> 4, ul = rem & 15;
        int u = blk * 16 + ul;
        int srcrow = g * 512 + u;
        float v = (k < TWOD) ? Wih[srcrow * TWOD + k] : Whh[srcrow * FOURD + (k - TWOD)];
        Wbf[i] = f2bf(v);
    }
    for (int n = idx; n < NGATE; n += stride) {
        int blk = n >> 6, rem = n & 63;
        int g = rem >> 4, ul = rem & 15;
        int u = blk * 16 + ul;
        int srcrow = g * 512 + u;
        biasR[n] = bih[srcrow] + bhh[srcrow];
    }
    for (int i = idx; i < FOURD * TWOD; i += stride) {
        int o = i / TWOD, j = i % TWOD;
        p1WT[j * FOURD + o] = p1W[o * TWOD + j];
    }
    for (int i = idx; i < TWOD * FOURD; i += stride) {
        int o = i / FOURD, j = i % FOURD;
        p2WT[j * TWOD + o] = p2W[o * FOURD + j];
    }
    for (int i = idx; i < 2 * DD * TWOD; i += stride) {
        float v = (i < DD * TWOD) ? nW[i] : nvW[i - DD * TWOD];
        Nbf[i] = f2bf(v);
    }
}

// ---------------- K1 v5: neighbor encoder, async fp32 gather via global_load_lds
// Block = UPB units x both paths. Waves: w>>1 = path, w&1 = n-half.
// Stage 4 row-groups (rel_e, ent_e, rel_v, ent_v) as fp32 [32][128] in LDS via
// global_load_lds (zero VGPR landing space -> all 16 x 1KiB issues in flight,
// ONE latency exposure per unit instead of register-pressure-serialized rounds).
// Row stride 512B would be a 16-way bank conflict on fragment reads, so the
// per-lane GLOBAL source is pre-swizzled (16B-block index ^ (row&7)) and every
// read applies the same XOR (m173 pattern). bf16 conversion moves to the
// fragment read (2x ds_read_b128 + pack8). Pooling reads fp32 ent_e directly.
__global__ __launch_bounds__(256, 2) void k_neighbor_v5(
    const float* __restrict__ emb, const float* __restrict__ emb_var,
    const unsigned short* __restrict__ Nbf,
    const float* __restrict__ nWb, const float* __restrict__ nu,
    const float* __restrict__ nvWb, const float* __restrict__ nvu,
    const int* __restrict__ q_left, const int* __restrict__ q_right,
    const int* __restrict__ s_left, const int* __restrict__ s_right,
    float* __restrict__ query, float* __restrict__ support)
{
    const int tid  = threadIdx.x;
    const int wave = tid >> 6, lane = tid & 63;
    const int quad = lane >> 4, m15 = lane & 15;
    const int pw   = wave >> 1;          // path of this wave (MFMA phase)
    const int wn   = wave & 1;           // n-half
    const int u0   = blockIdx.x * UPB;

    __shared__ __align__(16) float Sgf[4 * 32 * DD];   // 64 KiB, linear, src-swizzled
    __shared__ int   sidxL[UPB][64];
    __shared__ float aP[2][2][32];
    __shared__ float attL[2][32];

    // ---- block init: neighbor indices for all UPB units ----
    {
        int un = tid >> 6, i = tid & 63;
        int uu_ = u0 + un; if (uu_ >= TOTU) uu_ = TOTU - 1;
        const int* conn;
        if (uu_ < BQ)                 conn = q_left  + uu_ * (NBN * 2);
        else if (uu_ < 2 * BQ)        conn = q_right + (uu_ - BQ) * (NBN * 2);
        else if (uu_ < 2 * BQ + FEWN) conn = s_left  + (uu_ - 2 * BQ) * (NBN * 2);
        else                          conn = s_right + (uu_ - 2 * BQ - FEWN) * (NBN * 2);
        sidxL[un][i] = (i < NBN * 2) ? conn[i] : NSYM;
    }

    // ---- per-wave constants: B fragments (128 VGPR), u & bias slices ----
    const unsigned short* Bw = Nbf + (size_t)pw * DD * TWOD;
    const float* Wb = pw ? nvWb : nWb;
    const float* uu = pw ? nvu  : nu;
    bf16x8 Bf[4][8];
    float nb[4], un_[4];
#pragma unroll
    for (int t = 0; t < 4; ++t) {
        int n = wn * 64 + t * 16 + m15;
#pragma unroll
        for (int kt = 0; kt < 8; ++kt)
            Bf[t][kt] = *(const bf16x8*)(Bw + n * TWOD + kt * 32 + quad * 8);
        nb[t] = Wb[n];
        un_[t] = uu[n];
    }
    __syncthreads();

    for (int r = 0; r < UPB; ++r) {
        const int uidx = u0 + r;

        // ---- stage: group = wave; 32 rows x 128 fp32, async direct-to-LDS ----
        {
            const int g = wave;
            const float* table = (g < 2) ? emb : emb_var;
            const int side = g & 1;
            const int rl = lane >> 5;        // row within the 2-row/instr pair
            const int cb = lane & 31;        // dest 16B-block within row
#pragma unroll
            for (int i = 0; i < 16; ++i) {
                const int row = 2 * i + rl;
                const int sym = sidxL[r][2 * row + side];
                const float* src = table + (size_t)sym * DD + ((cb ^ (row & 7)) << 2);
                gload_lds16(src, &Sgf[(g * 32 + 2 * i) * DD]);
            }
        }
        __syncthreads();

        // ---- MFMA: S[32x64 per wave] = cat * W^T (convert fp32->bf16 on read) ----
        const int pg = pw ? 2 : 0;
        f32x4 acc[2][4] = {};
#pragma unroll
        for (int kt = 0; kt < 8; ++kt) {
            const int g = (kt < 4) ? pg : pg + 1;
            const int cb0 = (kt & 3) * 8 + quad * 2;   // 16B-block of first half
            bf16x8 fa[2];
#pragma unroll
            for (int mt = 0; mt < 2; ++mt) {
                const int row = mt * 16 + m15;
                const float* rp = &Sgf[(g * 32 + row) * DD];
                const int s = row & 7;
                float4 x0 = *(const float4*)(rp + ((cb0 ^ s) << 2));
                float4 x1 = *(const float4*)(rp + (((cb0 + 1) ^ s) << 2));
                fa[mt] = pack8(x0, x1);
            }
#pragma unroll
            for (int mt = 0; mt < 2; ++mt)
#pragma unroll
                for (int nt = 0; nt < 4; ++nt)
                    acc[mt][nt] = __builtin_amdgcn_mfma_f32_16x16x32_bf16(fa[mt], Bf[nt][kt], acc[mt][nt], 0, 0, 0);
        }

        // ---- epilogue: partial a[m] = sum_n u[n]*tanh(S+b) over this n-half ----
        {
            float part[2][4];
#pragma unroll
            for (int mt = 0; mt < 2; ++mt)
#pragma unroll
                for (int rr = 0; rr < 4; ++rr) {
                    float s = 0.f;
#pragma unroll
                    for (int nt = 0; nt < 4; ++nt)
                        s += un_[nt] * ftanh(acc[mt][nt][rr] + nb[nt]);
                    part[mt][rr] = s;
                }
#pragma unroll
            for (int off = 1; off < 16; off <<= 1)
#pragma unroll
                for (int mt = 0; mt < 2; ++mt)
#pragma unroll
                    for (int rr = 0; rr < 4; ++rr)
                        part[mt][rr] += __shfl_xor(part[mt][rr], off, 64);
            if (m15 == 0) {
#pragma unroll
                for (int mt = 0; mt < 2; ++mt)
#pragma unroll
                    for (int rr = 0; rr < 4; ++rr)
                        aP[pw][wn][mt * 16 + quad * 4 + rr] = part[mt][rr];
            }
        }
        __syncthreads();

        // ---- softmax over 30 neighbors: wave 0 -> p0, wave 2 -> p1 ----
        if ((wave & 1) == 0 && lane < 32) {
            const int p = wave >> 1;
            float sc = (lane < NBN) ? aP[p][0][lane] + aP[p][1][lane] : -1e30f;
            float mx = sc;
#pragma unroll
            for (int off = 1; off < 32; off <<= 1) mx = fmaxf(mx, __shfl_xor(mx, off, 64));
            float e = (lane < NBN) ? __expf(sc - mx) : 0.f;
            float sum = e;
#pragma unroll
            for (int off = 1; off < 32; off <<= 1) sum += __shfl_xor(sum, off, 64);
            attL[p][lane] = e / sum;
        }
        __syncthreads();

        // ---- pool ent_e (group 1, fp32, from emb — both paths) + tanh + store ----
        {
            const int p = tid >> 7;          // waves 0,1 -> p0; waves 2,3 -> p1
            const int d = tid & 127;
            const int cbp = d >> 2, ofs = d & 3;
            float pool = 0.f;
#pragma unroll
            for (int k = 0; k < NBN; ++k)
                pool += attL[p][k] * Sgf[(32 + k) * DD + ((cbp ^ (k & 7)) << 2) + ofs];
            if (uidx < TOTU) {
                float* dst;
                if (uidx < BQ)                 dst = query   + ((size_t)p * BQ + uidx) * TWOD;
                else if (uidx < 2 * BQ)        dst = query   + ((size_t)p * BQ + (uidx - BQ)) * TWOD + DD;
                else if (uidx < 2 * BQ + FEWN) dst = support + ((size_t)p * FEWN + (uidx - 2 * BQ)) * TWOD;
                else                           dst = support + ((size_t)p * FEWN + (uidx - 2 * BQ - FEWN)) * TWOD + DD;
                dst[d] = ftanh(pool);
            }
        }
        __syncthreads();   // protect Sgf before next unit's staging
    }
}

// ---------------- K2: support encoder (MLP + residual + layernorm ddof=1) ------
template <int RPB>
__global__ __launch_bounds__(256) void k_supenc(
    const float* __restrict__ xin, float* __restrict__ xout,
    unsigned short* __restrict__ abf,
    const float* __restrict__ p1WT, const float* __restrict__ p1b,
    const float* __restrict__ p2WT, const float* __restrict__ p2b,
    const float* __restrict__ ln_a, const float* __restrict__ ln_b)
{
    const int tid = threadIdx.x;
    const int r0 = blockIdx.x * RPB;
    __shared__ float X[RPB][TWOD];
    __shared__ float H1[RPB][FOURD];
    __shared__ float red[4][RPB][2];
    __shared__ float muv[RPB], sgv[RPB];

    for (int idx = tid; idx < RPB * TWOD; idx += 256) {
        int r = idx >> 8, j = idx & 255;
        X[r][j] = xin[(size_t)(r0 + r) * TWOD + j];
    }
    __syncthreads();

    {
        float acc[RPB][2] = {};
        for (int j = 0; j < TWOD; j += 4) {
            float w0[4], w1[4];
#pragma unroll
            for (int jj = 0; jj < 4; ++jj) {
                w0[jj] = p1WT[(j + jj) * FOURD + tid];
                w1[jj] = p1WT[(j + jj) * FOURD + tid + 256];
            }
#pragma unroll
            for (int r = 0; r < RPB; ++r) {
                float x[4] __attribute__((aligned(16)));
                *(float4*)x = *(const float4*)&X[r][j];
#pragma unroll
                for (int jj = 0; jj < 4; ++jj) {
                    acc[r][0] += x[jj] * w0[jj];
                    acc[r][1] += x[jj] * w1[jj];
                }
            }
        }
        float b0 = p1b[tid], b1 = p1b[tid + 256];
#pragma unroll
        for (int r = 0; r < RPB; ++r) {
            H1[r][tid]       = fmaxf(acc[r][0] + b0, 0.f);
            H1[r][tid + 256] = fmaxf(acc[r][1] + b1, 0.f);
        }
    }
    __syncthreads();

    float z[RPB];
    {
        float acc[RPB] = {};
        for (int j = 0; j < FOURD; j += 4) {
            float w[4];
#pragma unroll
            for (int jj = 0; jj < 4; ++jj) w[jj] = p2WT[(j + jj) * TWOD + tid];
#pragma unroll
            for (int r = 0; r < RPB; ++r) {
                float h[4] __attribute__((aligned(16)));
                *(float4*)h = *(const float4*)&H1[r][j];
#pragma unroll
                for (int jj = 0; jj < 4; ++jj) acc[r] += h[jj] * w[jj];
            }
        }
        float b = p2b[tid];
#pragma unroll
        for (int r = 0; r < RPB; ++r) z[r] = acc[r] + b + X[r][tid];
    }
    {
        float s[RPB], ss[RPB];
#pragma unroll
        for (int r = 0; r < RPB; ++r) { s[r] = z[r]; ss[r] = z[r] * z[r]; }
#pragma unroll
        for (int off = 1; off < 64; off <<= 1)
#pragma unroll
            for (int r = 0; r < RPB; ++r) {
                s[r]  += __shfl_xor(s[r],  off, 64);
                ss[r] += __shfl_xor(ss[r], off, 64);
            }
        const int wv = tid >> 6, lane = tid & 63;
        if (lane == 0) {
#pragma unroll
            for (int r = 0; r < RPB; ++r) { red[wv][r][0] = s[r]; red[wv][r][1] = ss[r]; }
        }
        __syncthreads();
        if (tid < RPB) {
            float st  = red[0][tid][0] + red[1][tid][0] + red[2][tid][0] + red[3][tid][0];
            float sst = red[0][tid][1] + red[1][tid][1] + red[2][tid][1] + red[3][tid][1];
            float mu  = st / (float)TWOD;
            float var = fmaxf((sst - (float)TWOD * mu * mu) / ((float)TWOD - 1.f), 0.f);
            muv[tid] = mu; sgv[tid] = sqrtf(var);
        }
        __syncthreads();
    }
#pragma unroll
    for (int r = 0; r < RPB; ++r) {
        float o = (z[r] - muv[r]) / (sgv[r] + 1e-3f) * ln_a[tid] + ln_b[tid];
        xout[(size_t)(r0 + r) * TWOD + tid] = o;
        if (abf) abf[(size_t)(r0 + r) * KTOT + tid] = f2bf(o);
    }
}

// ---------------- K4a: LSTM gates via bf16 MFMA, fused cell update -------------
// nkt = number of 32-wide K tiles. Step 0 runs with nkt=8 (K=256): h_r=0, c=0,
// so the h|r two-thirds of K would multiply zeros — skip them entirely.
__global__ __launch_bounds__(256) void k_lstm_mfma(
    const unsigned short* __restrict__ Abf,
    const unsigned short* __restrict__ Wbf,
    const float* __restrict__ biasR,
    float* __restrict__ cst, float* __restrict__ hbuf,
    const int nkt)
{
    __shared__ __align__(16) unsigned short As[128 * 32];
    __shared__ __align__(16) unsigned short Bs[128 * 32];
    const int tid  = threadIdx.x;
    const int wave = tid >> 6, lane = tid & 63;
    const int quad = lane >> 4, m15 = lane & 15;
    const int m0 = blockIdx.x * 128;
    const int n0 = blockIdx.y * 128;
    const int wm = wave >> 1, wn = wave & 1;
    const int lrow = lane >> 2, lslot = lane & 3;

    f32x4 acc[4][4] = {};

    for (int kt = 0; kt < nkt; ++kt) {
        const int k0 = kt * 32;
        __syncthreads();
#pragma unroll
        for (int t = 0; t < 2; ++t) {
            int c = wave * 2 + t;
            int row = c * 16 + lrow;
            int kg = lslot ^ ((row >> 1) & 3);
            gload_lds16(Abf + (size_t)(m0 + row) * KTOT + k0 + kg * 8, As + c * 512);
            gload_lds16(Wbf + (size_t)(n0 + row) * KTOT + k0 + kg * 8, Bs + c * 512);
        }
        __syncthreads();

        bf16x8 fa[4], fb[4];
#pragma unroll
        for (int mi = 0; mi < 4; ++mi) {
            int ra = wm * 64 + mi * 16 + m15;
            int sa = quad ^ ((ra >> 1) & 3);
            fa[mi] = *(const bf16x8*)(As + ra * 32 + sa * 8);
            int rb = wn * 64 + mi * 16 + m15;
            int sb = quad ^ ((rb >> 1) & 3);
            fb[mi] = *(const bf16x8*)(Bs + rb * 32 + sb * 8);
        }
#pragma unroll
        for (int mi = 0; mi < 4; ++mi)
#pragma unroll
            for (int ni = 0; ni < 4; ++ni)
                acc[mi][ni] = __builtin_amdgcn_mfma_f32_16x16x32_bf16(fa[mi], fb[ni], acc[mi][ni], 0, 0, 0);
    }

    const int u = ((n0 + wn * 64) >> 2) + m15;
    float bg[4];
#pragma unroll
    for (int g = 0; g < 4; ++g) bg[g] = biasR[n0 + wn * 64 + g * 16 + m15];
#pragma unroll
    for (int mi = 0; mi < 4; ++mi) {
#pragma unroll
        for (int r = 0; r < 4; ++r) {
            int gm = m0 + wm * 64 + mi * 16 + quad * 4 + r;
            size_t cidx = (size_t)gm * ULIVE + u;
            float pi = acc[mi][0][r] + bg[0];
            float pf = acc[mi][1][r] + bg[1];
            float pg = acc[mi][2][r] + bg[2];
            float po = acc[mi][3][r] + bg[3];
            float cn = sigmoidf_(pf) * cst[cidx] + sigmoidf_(pi) * tanhf(pg);
            cst[cidx]  = cn;
            hbuf[cidx] = sigmoidf_(po) * tanhf(cn);
        }
    }
}

// ---------------- K4b: h, attention over support, write bf16 h|r ---------------
__global__ __launch_bounds__(256) void k_lstm_attn(
    const float* __restrict__ qg, const float* __restrict__ hbuf,
    const float* __restrict__ sg, unsigned short* __restrict__ Abf,
    float* __restrict__ hfin)
{
    const int tid = threadIdx.x;
    const int p   = blockIdx.y;
    const int wv = tid >> 6, lane = tid & 63;
    __shared__ float sgl[FEWN][TWOD];
    for (int idx = tid; idx < FEWN * TWOD; idx += 256)
        sgl[idx >> 8][idx & 255] = sg[p * FEWN * TWOD + idx];
    __syncthreads();
    const int j0 = lane * 4;
    for (int rr = 0; rr < 8; ++rr) {
        int row = blockIdx.x * 32 + wv * 8 + rr;
        size_t g = (size_t)p * BQ + row;
        float4 q4 = *(const float4*)(qg + g * TWOD + j0);
        float4 t4 = *(const float4*)(hbuf + g * ULIVE + j0);
        float h[4] __attribute__((aligned(16))) = {q4.x + t4.x, q4.y + t4.y, q4.z + t4.z, q4.w + t4.w};
        float sv[FEWN][4] __attribute__((aligned(16)));
        float pa[FEWN];
#pragma unroll
        for (int f = 0; f < FEWN; ++f) {
            *(float4*)sv[f] = *(const float4*)&sgl[f][j0];
            pa[f] = h[0] * sv[f][0] + h[1] * sv[f][1] + h[2] * sv[f][2] + h[3] * sv[f][3];
        }
#pragma unroll
        for (int off = 1; off < 64; off <<= 1)
#pragma unroll
            for (int f = 0; f < FEWN; ++f) pa[f] += __shfl_xor(pa[f], off, 64);
        float mx = pa[0];
#pragma unroll
        for (int f = 1; f < FEWN; ++f) mx = fmaxf(mx, pa[f]);
        float sum = 0.f, e[FEWN];
#pragma unroll
        for (int f = 0; f < FEWN; ++f) { e[f] = expf(pa[f] - mx); sum += e[f]; }
        float inv = 1.f / sum;
        float r4[4] __attribute__((aligned(16))) = {0.f, 0.f, 0.f, 0.f};
#pragma unroll
        for (int f = 0; f < FEWN; ++f) {
            float a = e[f] * inv;
#pragma unroll
            for (int q = 0; q < 4; ++q) r4[q] += a * sv[f][q];
        }
        unsigned short tb[4] __attribute__((aligned(8)));
#pragma unroll
        for (int q = 0; q < 4; ++q) tb[q] = f2bf(h[q]);
        *(uint2*)(Abf + g * KTOT + TWOD + j0) = *(uint2*)tb;
#pragma unroll
        for (int q = 0; q < 4; ++q) tb[q] = f2bf(r4[q]);
        *(uint2*)(Abf + g * KTOT + FOURD + j0) = *(uint2*)tb;
        *(float4*)(hfin + g * TWOD + j0) = *(float4*)h;
    }
}

// ---------------- K5: final scores ---------------------------------------------
__global__ __launch_bounds__(256) void k_score(
    const float* __restrict__ hfin, const float* __restrict__ sg, float* __restrict__ out)
{
    const int tid = threadIdx.x;
    const int p   = blockIdx.y;
    __shared__ float sm[TWOD];
    if (tid < TWOD) {
        const float* s = sg + p * FEWN * TWOD + tid;
        sm[tid] = (s[0] + s[TWOD] + s[2 * TWOD] + s[3 * TWOD] + s[4 * TWOD]) / 5.0f;
    }
    __syncthreads();
    const int wv = tid >> 6, lane = tid & 63;
    const int j0 = lane * 4;
    for (int rr = 0; rr < 8; ++rr) {
        int row = blockIdx.x * 32 + wv * 8 + rr;
        const float* h = hfin + ((size_t)p * BQ + row) * TWOD + j0;
        float4 h4 = *(const float4*)h;
        float4 s4 = *(const float4*)&sm[j0];
        float pv = h4.x * s4.x + h4.y * s4.y + h4.z * s4.z + h4.w * s4.w;
#pragma unroll
        for (int off = 1; off < 64; off <<= 1) pv += __shfl_xor(pv, off, 64);
        if (lane == 0) out[p * BQ + row] = pv;
    }
}

extern "C" void kernel_launch(void* const* d_in, const int* in_sizes, int n_in,
                              void* d_out, int out_size, void* d_ws, size_t ws_size,
                              hipStream_t stream)
{
    const float* emb     = (const float*)d_in[0];
    const float* emb_var = (const float*)d_in[1];
    const float* nW      = (const float*)d_in[2];
    const float* nWb     = (const float*)d_in[3];
    const float* nu      = (const float*)d_in[4];
    const float* nub     = (const float*)d_in[5];
    const float* nvW     = (const float*)d_in[6];
    const float* nvWb    = (const float*)d_in[7];
    const float* nvu     = (const float*)d_in[8];
    const float* nvub    = (const float*)d_in[9];
    const float* p1W     = (const float*)d_in[10];
    const float* p1b     = (const float*)d_in[11];
    const float* p2W     = (const float*)d_in[12];
    const float* p2b     = (const float*)d_in[13];
    const float* ln_a    = (const float*)d_in[14];
    const float* ln_b    = (const float*)d_in[15];
    const float* Wih     = (const float*)d_in[16];
    const float* Whh     = (const float*)d_in[17];
    const float* bih     = (const float*)d_in[18];
    const float* bhh     = (const float*)d_in[19];
    const int* q_left    = (const int*)d_in[20];
    const int* q_right   = (const int*)d_in[21];
    const int* s_left    = (const int*)d_in[22];
    const int* s_right   = (const int*)d_in[23];

    float* ws = (float*)d_ws;
    size_t o = 0;
    float* p1WT     = ws + o; o += FOURD * TWOD;
    float* p2WT     = ws + o; o += FOURD * TWOD;
    float* biasR    = ws + o; o += NGATE;
    float* query    = ws + o; o += (size_t)2 * BQ * TWOD;    // reused as hfin
    float* supportB = ws + o; o += 2 * FEWN * TWOD;
    float* qg       = ws + o; o += (size_t)2 * BQ * TWOD;
    float* sg       = ws + o; o += 2 * FEWN * TWOD;
    float* cst      = ws + o; o += (size_t)2 * BQ * ULIVE;
    float* hbuf     = ws + o; o += (size_t)2 * BQ * ULIVE;
    unsigned short* Wbf = (unsigned short*)(ws + o); o += (size_t)NGATE * KTOT / 2;
    unsigned short* Abf = (unsigned short*)(ws + o); o += (size_t)2 * BQ * KTOT / 2;
    unsigned short* Nbf = (unsigned short*)(ws + o); o += (size_t)2 * DD * TWOD / 2;
    float* hfin     = query;

    // cst must be zero for step 0 (f-gate multiplies it). Abf memset dropped:
    // step 0 runs K=256 (never reads h|r), and k_lstm_attn fully writes h|r
    // for every row before step 1 reads it.
    hipMemsetAsync(cst, 0, (size_t)2 * BQ * ULIVE * sizeof(float), stream);

    k_prep<<<dim3(1024), dim3(256), 0, stream>>>(Wih, Whh, bih, bhh, p1W, p2W, nW, nvW,
                                                 Wbf, biasR, p1WT, p2WT, Nbf);
    k_neighbor_v5<<<dim3((TOTU + UPB - 1) / UPB), dim3(256), 0, stream>>>(
        emb, emb_var, Nbf, nWb, nu, nvWb, nvu,
        q_left, q_right, s_left, s_right, query, supportB);
    k_supenc<8><<<dim3(2 * BQ / 8), dim3(256), 0, stream>>>(query, qg, Abf, p1WT, p1b, p2WT, p2b, ln_a, ln_b);
    k_supenc<1><<<dim3(2 * FEWN), dim3(256), 0, stream>>>(supportB, sg, (unsigned short*)nullptr,
                                                          p1WT, p1b, p2WT, p2b, ln_a, ln_b);
    for (int s = 0; s < 4; ++s) {
        k_lstm_mfma<<<dim3(2 * BQ / 128, NGATE / 128), dim3(256), 0, stream>>>(
            Abf, Wbf, biasR, cst, hbuf, s == 0 ? TWOD / 32 : KTOT / 32);
        k_lstm_attn<<<dim3(BQ / 32, 2), dim3(256), 0, stream>>>(qg, hbuf, sg, Abf, hfin);
    }
    k_score<<<dim3(BQ / 32, 2), dim3(256), 0, stream>>>(hfin, sg, (float*)d_out);
}